// Round 8
// baseline (33.368 us; speedup 1.0000x reference)
//
#include <hip/hip_runtime.h>
#include <math.h>

namespace {

constexpr int NOUT = 10240;
constexpr int OW   = 4;      // o's per block (one per wave)
constexpr int NB   = 4;      // batch
constexpr int NIJ  = 16;     // so*si receptive field
constexpr int NPD  = 16;     // n_phi * n_dist
constexpr int NC   = 32;     // channels
constexpr int NIN  = NOUT * NIJ;
constexpr int WPAD = 20;     // padded ij-stride for s_w (conflict-free float4 reads)

typedef float vfloat4 __attribute__((ext_vector_type(4)));  // native vec for nt-store

__device__ __forceinline__ void fma4(float4& a, float s, const float4& v) {
    a.x = fmaf(s, v.x, a.x);
    a.y = fmaf(s, v.y, a.y);
    a.z = fmaf(s, v.z, a.z);
    a.w = fmaf(s, v.w, a.w);
}

__device__ __forceinline__ void nt_store4(float4* p, const float4& v) {
    vfloat4 nv = { v.x, v.y, v.z, v.w };
    __builtin_nontemporal_store(nv, reinterpret_cast<vfloat4*>(p));
}

__global__ __launch_bounds__(256) void polnorm_kernel(
    const float* __restrict__ x,        // (B, NIN, 1, 1, NC)
    const float* __restrict__ cx,       // (1, NOUT, 4, 4)
    const float* __restrict__ cy,       // (1, NOUT, 4, 4)
    const float* __restrict__ phis,     // (4,)
    const float* __restrict__ dists_p,  // (4,)
    const float* __restrict__ sigma_p,  // (1,)
    float* __restrict__ out)            // (B, NOUT, 1, 4, 4, 1, NC)
{
    // All wave-private regions: NO __syncthreads in this kernel.
    __shared__ __align__(16) float s_w[OW][NPD][WPAD];  // per-wave raw weights
    __shared__ __align__(16) float s_x[OW][NIJ * NC];   // per-wave 2KB x bounce

    const int t   = threadIdx.x;
    const int wid = t >> 6;       // wave id -> which o of this block
    const int l   = t & 63;       // lane
    const int c4  = l & 7;        // float4 channel slot
    const int pda = l >> 3;       // pd for acc0 (0..7); acc1 uses pda+8

    const int o = blockIdx.x * OW + wid;

    const float4* xg = reinterpret_cast<const float4*>(x) + (size_t)o * (NIJ * NC / 4);
    float4*       og = reinterpret_cast<float4*>(out)     + (size_t)o * (NPD * NC / 4);
    const size_t xstride = (size_t)NIN * NC / 4;          // float4 step per b
    const size_t ostride = (size_t)NOUT * NPD * NC / 4;   // float4 step per b

    // issue b=0 and b=1 x loads FIRST — latency hides under the fill phase
    float4 f0 = xg[l];
    float4 f1 = xg[64 + l];
    float4 g0 = xg[xstride + l];
    float4 g1 = xg[xstride + 64 + l];

    // ---------- fill: wave-private w for this wave's single o ----------
    float inv0, inv1;
    {
        const int pdf = l >> 2;          // 0..15 (pd), 4 lanes per pd
        const int ijq = (l & 3) * 4;     // ij base, 4 ij per lane
        const int p = pdf >> 2, dd = pdf & 3;

        const float dist = 2.0f / (1.0f + expf(-dists_p[dd]));  // 2*sigmoid
        const float phi  = phis[p];
        const float mux  = cosf(phi) * dist;
        const float muy  = sinf(phi) * dist;
        float sg = 2.0f / (1.0f + expf(-sigma_p[0]));
        sg = fmaxf(sg, 1e-10f);
        const float coef = -0.5f / (sg * sg);

        const float4 cxi = *reinterpret_cast<const float4*>(&cx[o * NIJ + ijq]);
        const float4 cyi = *reinterpret_cast<const float4*>(&cy[o * NIJ + ijq]);

        float4 w;
        { float dx = cxi.x - mux, dy = cyi.x - muy; w.x = expf(coef * (dx*dx + dy*dy)); }
        { float dx = cxi.y - mux, dy = cyi.y - muy; w.y = expf(coef * (dx*dx + dy*dy)); }
        { float dx = cxi.z - mux, dy = cyi.z - muy; w.z = expf(coef * (dx*dx + dy*dy)); }
        { float dx = cxi.w - mux, dy = cyi.w - muy; w.w = expf(coef * (dx*dx + dy*dy)); }

        float s = w.x + w.y + w.z + w.w;     // partial over this lane's 4 ij
        s += __shfl_xor(s, 1);               // reduce across the pd's 4 lanes
        s += __shfl_xor(s, 2);
        const float inv = 1.0f / (s + 1e-20f);

        *reinterpret_cast<float4*>(&s_w[wid][pdf][ijq]) = w;

        // redistribute inv to the main-phase lane mapping (pd = pda, pda+8)
        inv0 = __shfl(inv, pda * 4);
        inv1 = __shfl(inv, pda * 4 + 32);
    }
    // same-wave LDS write -> read: ordered by lgkmcnt, no barrier needed

    // ---------- main: loop over 4 b's with this wave's fixed w ----------
    float4* xs = reinterpret_cast<float4*>(s_x[wid]);   // 128 float4

    #pragma unroll
    for (int bi = 0; bi < NB; ++bi) {
        // stage current b into LDS (same-wave bounce)
        xs[l] = f0;
        xs[64 + l] = f1;

        // rotate pipeline: f <- g, issue b+2's loads into g
        f0 = g0; f1 = g1;
        if (bi + 2 < NB) {
            g0 = xg[(size_t)(bi + 2) * xstride + l];
            g1 = xg[(size_t)(bi + 2) * xstride + 64 + l];
        }

        float4 acc0 = make_float4(0.f, 0.f, 0.f, 0.f);
        float4 acc1 = make_float4(0.f, 0.f, 0.f, 0.f);

        #pragma unroll
        for (int kk = 0; kk < 4; ++kk) {
            const float4 wa = *reinterpret_cast<const float4*>(&s_w[wid][pda][kk * 4]);
            const float4 wb = *reinterpret_cast<const float4*>(&s_w[wid][pda + 8][kk * 4]);
            const float4 xv0 = xs[(kk * 4 + 0) * 8 + c4];
            const float4 xv1 = xs[(kk * 4 + 1) * 8 + c4];
            const float4 xv2 = xs[(kk * 4 + 2) * 8 + c4];
            const float4 xv3 = xs[(kk * 4 + 3) * 8 + c4];
            fma4(acc0, wa.x, xv0); fma4(acc1, wb.x, xv0);
            fma4(acc0, wa.y, xv1); fma4(acc1, wb.y, xv1);
            fma4(acc0, wa.z, xv2); fma4(acc1, wb.z, xv2);
            fma4(acc0, wa.w, xv3); fma4(acc1, wb.w, xv3);
        }

        acc0.x *= inv0; acc0.y *= inv0; acc0.z *= inv0; acc0.w *= inv0;
        acc1.x *= inv1; acc1.y *= inv1; acc1.z *= inv1; acc1.w *= inv1;

        // streaming stores (write-once output)
        nt_store4(&og[(size_t)bi * ostride + l], acc0);
        nt_store4(&og[(size_t)bi * ostride + 64 + l], acc1);
    }
}

} // namespace

extern "C" void kernel_launch(void* const* d_in, const int* in_sizes, int n_in,
                              void* d_out, int out_size, void* d_ws, size_t ws_size,
                              hipStream_t stream) {
    const float* x  = (const float*)d_in[0];
    const float* cx = (const float*)d_in[1];
    const float* cy = (const float*)d_in[2];
    const float* ph = (const float*)d_in[3];
    const float* dp = (const float*)d_in[4];
    const float* sp = (const float*)d_in[5];
    float* out = (float*)d_out;

    dim3 grid(NOUT / OW);
    dim3 block(256);
    hipLaunchKernelGGL(polnorm_kernel, grid, block, 0, stream,
                       x, cx, cy, ph, dp, sp, out);
}

// Round 9
// 30.769 us; speedup vs baseline: 1.0845x; 1.0845x over previous
//
#include <hip/hip_runtime.h>
#include <math.h>

namespace {

constexpr int NOUT = 10240;
constexpr int OW   = 4;      // o's per block (one per wave)
constexpr int NB   = 4;      // batch
constexpr int NIJ  = 16;     // so*si receptive field
constexpr int NPD  = 16;     // n_phi * n_dist
constexpr int NC   = 32;     // channels
constexpr int NIN  = NOUT * NIJ;
constexpr int WPAD = 20;     // padded ij-stride for s_w (conflict-free float4 reads)

typedef float vfloat4 __attribute__((ext_vector_type(4)));  // native vec for nt-store

__device__ __forceinline__ void fma4(float4& a, float s, const float4& v) {
    a.x = fmaf(s, v.x, a.x);
    a.y = fmaf(s, v.y, a.y);
    a.z = fmaf(s, v.z, a.z);
    a.w = fmaf(s, v.w, a.w);
}

__device__ __forceinline__ void nt_store4(float4* p, const float4& v) {
    vfloat4 nv = { v.x, v.y, v.z, v.w };
    __builtin_nontemporal_store(nv, reinterpret_cast<vfloat4*>(p));
}

__global__ __launch_bounds__(256) void polnorm_kernel(
    const float* __restrict__ x,        // (B, NIN, 1, 1, NC)
    const float* __restrict__ cx,       // (1, NOUT, 4, 4)
    const float* __restrict__ cy,       // (1, NOUT, 4, 4)
    const float* __restrict__ phis,     // (4,)
    const float* __restrict__ dists_p,  // (4,)
    const float* __restrict__ sigma_p,  // (1,)
    float* __restrict__ out)            // (B, NOUT, 1, 4, 4, 1, NC)
{
    // All wave-private regions: NO __syncthreads in this kernel.
    __shared__ __align__(16) float s_w[OW][NPD][WPAD];  // per-wave w bounce
    __shared__ __align__(16) float s_x[OW][NIJ * NC];   // per-wave 2KB x bounce

    const int t   = threadIdx.x;
    const int wid = t >> 6;       // wave id -> which o of this block
    const int l   = t & 63;       // lane
    const int c4  = l & 7;        // float4 channel slot
    const int pda = l >> 3;       // pd for acc0 (0..7); acc1 uses pda+8

    const int o = blockIdx.x * OW + wid;

    const float4* xg = reinterpret_cast<const float4*>(x) + (size_t)o * (NIJ * NC / 4);
    float4*       og = reinterpret_cast<float4*>(out)     + (size_t)o * (NPD * NC / 4);
    const size_t xstride = (size_t)NIN * NC / 4;          // float4 step per b
    const size_t ostride = (size_t)NOUT * NPD * NC / 4;   // float4 step per b

    // ---- issue ALL 4 b's x loads first: 8KB/wave in flight, zero rotation ----
    float4 x0[NB], x1[NB];
    #pragma unroll
    for (int bi = 0; bi < NB; ++bi) {
        x0[bi] = xg[(size_t)bi * xstride + l];
        x1[bi] = xg[(size_t)bi * xstride + 64 + l];
    }

    // ---------- fill: wave-private w for this wave's single o ----------
    float inv0, inv1;
    {
        const int pdf = l >> 2;          // 0..15 (pd), 4 lanes per pd
        const int ijq = (l & 3) * 4;     // ij base, 4 ij per lane
        const int p = pdf >> 2, dd = pdf & 3;

        const float dist = 2.0f / (1.0f + expf(-dists_p[dd]));  // 2*sigmoid
        const float phi  = phis[p];
        const float mux  = cosf(phi) * dist;
        const float muy  = sinf(phi) * dist;
        float sg = 2.0f / (1.0f + expf(-sigma_p[0]));
        sg = fmaxf(sg, 1e-10f);
        const float coef = -0.5f / (sg * sg);

        const float4 cxi = *reinterpret_cast<const float4*>(&cx[o * NIJ + ijq]);
        const float4 cyi = *reinterpret_cast<const float4*>(&cy[o * NIJ + ijq]);

        float4 w;
        { float dx = cxi.x - mux, dy = cyi.x - muy; w.x = expf(coef * (dx*dx + dy*dy)); }
        { float dx = cxi.y - mux, dy = cyi.y - muy; w.y = expf(coef * (dx*dx + dy*dy)); }
        { float dx = cxi.z - mux, dy = cyi.z - muy; w.z = expf(coef * (dx*dx + dy*dy)); }
        { float dx = cxi.w - mux, dy = cyi.w - muy; w.w = expf(coef * (dx*dx + dy*dy)); }

        float s = w.x + w.y + w.z + w.w;     // partial over this lane's 4 ij
        s += __shfl_xor(s, 1);               // reduce across the pd's 4 lanes
        s += __shfl_xor(s, 2);
        const float inv = 1.0f / (s + 1e-20f);

        *reinterpret_cast<float4*>(&s_w[wid][pdf][ijq]) = w;

        // redistribute inv to the main-phase lane mapping (pd = pda, pda+8)
        inv0 = __shfl(inv, pda * 4);
        inv1 = __shfl(inv, pda * 4 + 32);
    }

    // ---- hoist this lane's two w rows into registers (once per wave) ----
    float4 wa[4], wb[4];
    #pragma unroll
    for (int kk = 0; kk < 4; ++kk) {
        wa[kk] = *reinterpret_cast<const float4*>(&s_w[wid][pda][kk * 4]);
        wb[kk] = *reinterpret_cast<const float4*>(&s_w[wid][pda + 8][kk * 4]);
    }

    // ---------- main: loop over 4 b's; LDS = 2 writes + 16 reads per b ----------
    float4* xs = reinterpret_cast<float4*>(s_x[wid]);   // 128 float4

    #pragma unroll
    for (int bi = 0; bi < NB; ++bi) {
        // stage this b into LDS (same-wave bounce; lgkmcnt orders write->read)
        xs[l] = x0[bi];
        xs[64 + l] = x1[bi];

        float4 acc0 = make_float4(0.f, 0.f, 0.f, 0.f);
        float4 acc1 = make_float4(0.f, 0.f, 0.f, 0.f);

        #pragma unroll
        for (int kk = 0; kk < 4; ++kk) {
            const float4 xv0 = xs[(kk * 4 + 0) * 8 + c4];
            const float4 xv1 = xs[(kk * 4 + 1) * 8 + c4];
            const float4 xv2 = xs[(kk * 4 + 2) * 8 + c4];
            const float4 xv3 = xs[(kk * 4 + 3) * 8 + c4];
            fma4(acc0, wa[kk].x, xv0); fma4(acc1, wb[kk].x, xv0);
            fma4(acc0, wa[kk].y, xv1); fma4(acc1, wb[kk].y, xv1);
            fma4(acc0, wa[kk].z, xv2); fma4(acc1, wb[kk].z, xv2);
            fma4(acc0, wa[kk].w, xv3); fma4(acc1, wb[kk].w, xv3);
        }

        acc0.x *= inv0; acc0.y *= inv0; acc0.z *= inv0; acc0.w *= inv0;
        acc1.x *= inv1; acc1.y *= inv1; acc1.z *= inv1; acc1.w *= inv1;

        nt_store4(&og[(size_t)bi * ostride + l], acc0);
        nt_store4(&og[(size_t)bi * ostride + 64 + l], acc1);
    }
}

} // namespace

extern "C" void kernel_launch(void* const* d_in, const int* in_sizes, int n_in,
                              void* d_out, int out_size, void* d_ws, size_t ws_size,
                              hipStream_t stream) {
    const float* x  = (const float*)d_in[0];
    const float* cx = (const float*)d_in[1];
    const float* cy = (const float*)d_in[2];
    const float* ph = (const float*)d_in[3];
    const float* dp = (const float*)d_in[4];
    const float* sp = (const float*)d_in[5];
    float* out = (float*)d_out;

    dim3 grid(NOUT / OW);
    dim3 block(256);
    hipLaunchKernelGGL(polnorm_kernel, grid, block, 0, stream,
                       x, cx, cy, ph, dp, sp, out);
}